// Round 8
// baseline (371.509 us; speedup 1.0000x reference)
//
#include <hip/hip_runtime.h>
#include <hip/hip_bf16.h>

#define B_      8
#define HH      32
#define WW      32
#define E_      256
#define HEADS_  8
#define KD_     32
#define FFN_    1024
#define NQ_     64
#define L_      1024
#define SCALING_ 0.17677669529663687f
#define LOG2E_  1.44269504088896340736f
#define EPS_    1e-6f

typedef short bf16x8 __attribute__((ext_vector_type(8)));
typedef float f32x4 __attribute__((ext_vector_type(4)));
typedef unsigned short ushort_t;

#if __has_builtin(__builtin_amdgcn_exp2f)
#define EXP2(x) __builtin_amdgcn_exp2f(x)
#else
#define EXP2(x) exp2f(x)
#endif

__device__ __forceinline__ ushort_t f2bf(float f) {
    __hip_bfloat16 h = __float2bfloat16(f);
    return *reinterpret_cast<ushort_t*>(&h);
}
__device__ __forceinline__ unsigned int pk2(float a, float b) {
    __hip_bfloat162 h = __float22bfloat162_rn(float2{a, b});
    return *reinterpret_cast<unsigned int*>(&h);
}

// ---- transpose depthwise weights to [tap][e] ----------------------------
__global__ void dwT_kernel(const float* __restrict__ lepe_w, const float* __restrict__ pos_w,
                           float* __restrict__ LWT, float* __restrict__ PWT) {
    int e = threadIdx.x;
#pragma unroll
    for (int t = 0; t < 25; ++t) LWT[t * 256 + e] = lepe_w[e * 25 + t];
#pragma unroll
    for (int t = 0; t < 9; ++t) PWT[t * 256 + e] = pos_w[e * 9 + t];
}

// ---- fused 3x3 depthwise conv + residual + LN (wave per row) ------------
__global__ __launch_bounds__(256) void posconv_ln2(
        const float* __restrict__ x, const float* __restrict__ PWT,
        const float* __restrict__ bias, const float* __restrict__ g,
        const float* __restrict__ bb, float* __restrict__ X, ushort_t* __restrict__ HN) {
    int tid = threadIdx.x;
    int wave = tid >> 6, lane = tid & 63;
    int b = blockIdx.x >> 8, rem = blockIdx.x & 255;
    int hh = rem >> 3, wg = rem & 7;
    int ww = wg * 4 + wave;
    int e = lane * 4;
    long row = ((long)(b * HH + hh)) * WW + ww;

    float4 bi = *reinterpret_cast<const float4*>(bias + e);
    float ax = bi.x, ay = bi.y, az = bi.z, aw = bi.w;
#pragma unroll
    for (int dh = 0; dh < 3; ++dh) {
        int h2 = hh + dh - 1; if (h2 < 0 || h2 >= HH) continue;
        float rx = 0.f, ry = 0.f, rz = 0.f, rw = 0.f;
#pragma unroll
        for (int dw = 0; dw < 3; ++dw) {
            int w2 = ww + dw - 1; if (w2 < 0 || w2 >= WW) continue;
            float4 v = *reinterpret_cast<const float4*>(x + (((long)(b * HH + h2)) * WW + w2) * E_ + e);
            float4 wt = *reinterpret_cast<const float4*>(PWT + (dh * 3 + dw) * 256 + e);
            rx += v.x * wt.x; ry += v.y * wt.y; rz += v.z * wt.z; rw += v.w * wt.w;
        }
        ax += rx; ay += ry; az += rz; aw += rw;
    }
    float4 x4 = *reinterpret_cast<const float4*>(x + row * E_ + e);
    float vx = x4.x + ax, vy = x4.y + ay, vz = x4.z + az, vw = x4.w + aw;
    float4 o4 = {vx, vy, vz, vw};
    *reinterpret_cast<float4*>(X + row * E_ + e) = o4;

    float s = vx + vy + vz + vw;
#pragma unroll
    for (int off = 1; off < 64; off <<= 1) s += __shfl_xor(s, off);
    float mean = s * (1.0f / E_);
    float dx = vx - mean, dy = vy - mean, dz = vz - mean, dw_ = vw - mean;
    float s2 = dx * dx + dy * dy + dz * dz + dw_ * dw_;
#pragma unroll
    for (int off = 1; off < 64; off <<= 1) s2 += __shfl_xor(s2, off);
    float r = rsqrtf(s2 * (1.0f / E_) + EPS_);
    float4 g4 = *reinterpret_cast<const float4*>(g + e);
    float4 b4 = *reinterpret_cast<const float4*>(bb + e);
    uint2 p;
    p.x = pk2(dx * r * g4.x + b4.x, dy * r * g4.y + b4.y);
    p.y = pk2(dz * r * g4.z + b4.z, dw_ * r * g4.w + b4.w);
    *reinterpret_cast<uint2*>(HN + row * E_ + e) = p;
}

// ---- 5x5 depthwise conv (wave per row, float4) --------------------------
__global__ __launch_bounds__(256) void lepe2(
        const float* __restrict__ v, const float* __restrict__ LWT,
        const float* __restrict__ bias, float* __restrict__ out) {
    int tid = threadIdx.x;
    int wave = tid >> 6, lane = tid & 63;
    int b = blockIdx.x >> 8, rem = blockIdx.x & 255;
    int hh = rem >> 3, wg = rem & 7;
    int ww = wg * 4 + wave;
    int e = lane * 4;
    long row = ((long)(b * HH + hh)) * WW + ww;

    float4 bi = *reinterpret_cast<const float4*>(bias + e);
    float ax = bi.x, ay = bi.y, az = bi.z, aw = bi.w;
#pragma unroll
    for (int dh = 0; dh < 5; ++dh) {
        int h2 = hh + dh - 2; if (h2 < 0 || h2 >= HH) continue;
        float rx = 0.f, ry = 0.f, rz = 0.f, rw = 0.f;
#pragma unroll
        for (int dw = 0; dw < 5; ++dw) {
            int w2 = ww + dw - 2; if (w2 < 0 || w2 >= WW) continue;
            float4 vv = *reinterpret_cast<const float4*>(v + (((long)(b * HH + h2)) * WW + w2) * E_ + e);
            float4 wt = *reinterpret_cast<const float4*>(LWT + (dh * 5 + dw) * 256 + e);
            rx += vv.x * wt.x; ry += vv.y * wt.y; rz += vv.z * wt.z; rw += vv.w * wt.w;
        }
        ax += rx; ay += ry; az += rz; aw += rw;
    }
    float4 o4 = {ax, ay, az, aw};
    *reinterpret_cast<float4*>(out + row * E_ + e) = o4;
}

// ---- LayerNorm v2: wave per row, f32 -> bf16 ----------------------------
__global__ __launch_bounds__(256) void ln2(
        const float* __restrict__ x, const float* __restrict__ g,
        const float* __restrict__ b, ushort_t* __restrict__ y) {
    int tid = threadIdx.x;
    int wave = tid >> 6, lane = tid & 63;
    long row = (long)blockIdx.x * 4 + wave;
    int e = lane * 4;
    float4 v4 = *reinterpret_cast<const float4*>(x + row * E_ + e);
    float s = v4.x + v4.y + v4.z + v4.w;
#pragma unroll
    for (int off = 1; off < 64; off <<= 1) s += __shfl_xor(s, off);
    float mean = s * (1.0f / E_);
    float dx = v4.x - mean, dy = v4.y - mean, dz = v4.z - mean, dw = v4.w - mean;
    float s2 = dx * dx + dy * dy + dz * dz + dw * dw;
#pragma unroll
    for (int off = 1; off < 64; off <<= 1) s2 += __shfl_xor(s2, off);
    float r = rsqrtf(s2 * (1.0f / E_) + EPS_);
    float4 g4 = *reinterpret_cast<const float4*>(g + e);
    float4 b4 = *reinterpret_cast<const float4*>(b + e);
    uint2 p;
    p.x = pk2(dx * r * g4.x + b4.x, dy * r * g4.y + b4.y);
    p.y = pk2(dz * r * g4.z + b4.z, dw * r * g4.w + b4.w);
    *reinterpret_cast<uint2*>(y + row * E_ + e) = p;
}

// ---- mask f32 -> bf16 * LOG2E (coalesced) -------------------------------
__global__ void maskcvt_kernel(const float* __restrict__ m, ushort_t* __restrict__ o) {
    long i = ((long)blockIdx.x * 256 + threadIdx.x) * 4;
    float4 v = *reinterpret_cast<const float4*>(m + i);
    uint2 p;
    p.x = pk2(v.x * LOG2E_, v.y * LOG2E_);
    p.y = pk2(v.z * LOG2E_, v.w * LOG2E_);
    *reinterpret_cast<uint2*>(o + i) = p;
}

// ---- convert all weights to bf16 once -----------------------------------
struct WTab { const float* src[8]; };
__global__ void wconv_kernel(WTab t, ushort_t* __restrict__ dst) {
    const int off[9] = {0, 65536, 131072, 196608, 262144, 524288, 786432, 983040, 1048576};
    long base = ((long)blockIdx.x * 256 + threadIdx.x) * 4;
    int r = 0;
#pragma unroll
    for (int i = 1; i < 8; ++i) r = (base >= off[i]) ? i : r;
    const float* s =
        r == 0 ? t.src[0] : r == 1 ? t.src[1] : r == 2 ? t.src[2] : r == 3 ? t.src[3] :
        r == 4 ? t.src[4] : r == 5 ? t.src[5] : r == 6 ? t.src[6] : t.src[7];
    float4 v = *reinterpret_cast<const float4*>(s + (base - off[r]));
    uint2 p;
    p.x = pk2(v.x, v.y);
    p.y = pk2(v.z, v.w);
    *reinterpret_cast<uint2*>(dst + base) = p;
}

// ---- MFMA GEMM v2: BM=64 BN=64 BK=64, bf16 A & W, register prefetch -----
template<int ACT, int THETA>
__global__ __launch_bounds__(256) void gemm2(
        const ushort_t* __restrict__ A, const ushort_t* __restrict__ W,
        const float* __restrict__ bias, ushort_t* __restrict__ Cb,
        float* __restrict__ Cf, const float* __restrict__ resid,
        int M, int N, int K, float scale, int scaleN,
        const float* __restrict__ sinp, const float* __restrict__ cosp) {
    __shared__ __align__(16) ushort_t As[64 * 72];
    __shared__ __align__(16) ushort_t Ws[64 * 72];
    int tid = threadIdx.x;
    int wave = tid >> 6, lane = tid & 63;
    int quad = lane >> 4, l16 = lane & 15;
    int wm = wave >> 1, wn = wave & 1;
    long mBase = (long)blockIdx.x * 64;
    long nBase = (long)blockIdx.y * 64;
    int row = tid >> 3, q = tid & 7;
    int row2 = (tid + 256) >> 3, q2 = (tid + 256) & 7;

    f32x4 acc[2][2];
#pragma unroll
    for (int i = 0; i < 2; ++i)
#pragma unroll
        for (int j = 0; j < 2; ++j) acc[i][j] = (f32x4){0.f, 0.f, 0.f, 0.f};

    int nT = K >> 6;
    uint4 a0 = *reinterpret_cast<const uint4*>(A + (mBase + row) * (long)K + q * 8);
    uint4 a1 = *reinterpret_cast<const uint4*>(A + (mBase + row2) * (long)K + q2 * 8);
    uint4 w0 = *reinterpret_cast<const uint4*>(W + (nBase + row) * (long)K + q * 8);
    uint4 w1 = *reinterpret_cast<const uint4*>(W + (nBase + row2) * (long)K + q2 * 8);

    for (int t = 0; t < nT; ++t) {
        *reinterpret_cast<uint4*>(&As[row * 72 + q * 8]) = a0;
        *reinterpret_cast<uint4*>(&As[row2 * 72 + q2 * 8]) = a1;
        *reinterpret_cast<uint4*>(&Ws[row * 72 + q * 8]) = w0;
        *reinterpret_cast<uint4*>(&Ws[row2 * 72 + q2 * 8]) = w1;
        __syncthreads();
        if (t + 1 < nT) {
            int kt = (t + 1) << 6;
            a0 = *reinterpret_cast<const uint4*>(A + (mBase + row) * (long)K + kt + q * 8);
            a1 = *reinterpret_cast<const uint4*>(A + (mBase + row2) * (long)K + kt + q2 * 8);
            w0 = *reinterpret_cast<const uint4*>(W + (nBase + row) * (long)K + kt + q * 8);
            w1 = *reinterpret_cast<const uint4*>(W + (nBase + row2) * (long)K + kt + q2 * 8);
        }
#pragma unroll
        for (int kk = 0; kk < 2; ++kk) {
            bf16x8 af[2], bfr[2];
#pragma unroll
            for (int i = 0; i < 2; ++i)
                af[i] = *reinterpret_cast<const bf16x8*>(&As[(wm * 32 + i * 16 + l16) * 72 + kk * 32 + quad * 8]);
#pragma unroll
            for (int j = 0; j < 2; ++j)
                bfr[j] = *reinterpret_cast<const bf16x8*>(&Ws[(wn * 32 + j * 16 + l16) * 72 + kk * 32 + quad * 8]);
#pragma unroll
            for (int i = 0; i < 2; ++i)
#pragma unroll
                for (int j = 0; j < 2; ++j)
                    acc[i][j] = __builtin_amdgcn_mfma_f32_16x16x32_bf16(af[i], bfr[j], acc[i][j], 0, 0, 0);
        }
        __syncthreads();
    }

#pragma unroll
    for (int i = 0; i < 2; ++i)
#pragma unroll
        for (int j = 0; j < 2; ++j) {
            long n = nBase + wn * 32 + j * 16 + l16;
            float bn = bias[n];
            float eff = (n < scaleN) ? scale : 1.0f;
#pragma unroll
            for (int r = 0; r < 4; ++r) {
                long m = mBase + wm * 32 + i * 16 + quad * 4 + r;
                float v = (acc[i][j][r] + bn) * eff;
                if (THETA) {
                    float other = __shfl_xor(v, 1);
                    int l = (int)(m & (L_ - 1));
                    int d = (int)(n & 31);
                    float cc = cosp[l * 32 + d], ss = sinp[l * 32 + d];
                    v = v * cc + ((n & 1) ? other : -other) * ss;
                }
                if (ACT) v = 0.5f * v * (1.0f + erff(v * 0.70710678118654752f));
                if (resid) v += resid[m * N + n];
                if (Cf) Cf[m * N + n] = v;
                if (Cb) Cb[m * N + n] = f2bf(v);
            }
        }
}

// ---- MFMA flash attention v4: S^T orientation ----------------------------
// mfma(kfrag, qfrag) -> C[key][q]; lane owns 4 consecutive keys for one q.
// mask: 8x dwordx2 prefetch; P: 8x ds_write_b64 packed; exp via v_exp (log2e
// pre-folded into K scale and mask).
__global__ __launch_bounds__(256) void attn4(
        const ushort_t* __restrict__ Q, int qs,
        const ushort_t* __restrict__ K, int ks,
        const ushort_t* __restrict__ V, int vs,
        const ushort_t* __restrict__ maskbf,
        const float* __restrict__ lepe, ushort_t* __restrict__ out, int nq) {
    __shared__ __align__(16) ushort_t Vt[2][32 * 136];
    __shared__ __align__(16) ushort_t Pl[4][16 * 136];
    int tid = threadIdx.x;
    int wave = tid >> 6, lane = tid & 63;
    int quad = lane >> 4, l16 = lane & 15;
    int qt = blockIdx.x, h = blockIdx.y, b = blockIdx.z;
    int qbase = qt * 64 + wave * 16;

    bf16x8 qfrag = *reinterpret_cast<const bf16x8*>(
        Q + ((long)b * nq + qbase + l16) * qs + h * KD_ + quad * 8);

    f32x4 acc_o[2];
    acc_o[0] = (f32x4){0.f, 0.f, 0.f, 0.f};
    acc_o[1] = (f32x4){0.f, 0.f, 0.f, 0.f};
    float lsum = 0.f;

    int kp = tid & 63;
    int dq = tid >> 6;

    const ushort_t* vp = V + ((long)b * L_ + 2 * kp) * vs + h * KD_ + dq * 8;
    uint4 ua = *reinterpret_cast<const uint4*>(vp);
    uint4 ub = *reinterpret_cast<const uint4*>(vp + vs);
    {
        const unsigned int* wa = reinterpret_cast<const unsigned int*>(&ua);
        const unsigned int* wb = reinterpret_cast<const unsigned int*>(&ub);
#pragma unroll
        for (int i = 0; i < 8; ++i) {
            unsigned int x16 = (wa[i >> 1] >> ((i & 1) * 16)) & 0xFFFF;
            unsigned int y16 = (wb[i >> 1] >> ((i & 1) * 16)) & 0xFFFF;
            *reinterpret_cast<unsigned int*>(&Vt[0][(dq * 8 + i) * 136 + 2 * kp]) =
                x16 | (y16 << 16);
        }
    }

    for (int it = 0; it < 8; ++it) {
        int kb = it * 128;
        __syncthreads();
        // prefetch next V tile + this iter's mask rows (coalesced dwordx2)
        if (it < 7) {
            const ushort_t* vn = V + ((long)b * L_ + kb + 128 + 2 * kp) * vs + h * KD_ + dq * 8;
            ua = *reinterpret_cast<const uint4*>(vn);
            ub = *reinterpret_cast<const uint4*>(vn + vs);
        }
        uint2 mreg[8];
        if (maskbf) {
            const ushort_t* mb = maskbf + ((long)h * L_ + qbase + l16) * L_ + kb + quad * 4;
#pragma unroll
            for (int kt = 0; kt < 8; ++kt)
                mreg[kt] = *reinterpret_cast<const uint2*>(mb + kt * 16);
        }

        // S^T phase: two groups of 4 key-tiles with prefetched K frags
#pragma unroll
        for (int g = 0; g < 2; ++g) {
            bf16x8 kf[4];
#pragma unroll
            for (int kt4 = 0; kt4 < 4; ++kt4)
                kf[kt4] = *reinterpret_cast<const bf16x8*>(
                    K + ((long)b * L_ + kb + (g * 4 + kt4) * 16 + l16) * ks + h * KD_ + quad * 8);
#pragma unroll
            for (int kt4 = 0; kt4 < 4; ++kt4) {
                int kt = g * 4 + kt4;
                f32x4 sa = (f32x4){0.f, 0.f, 0.f, 0.f};
                sa = __builtin_amdgcn_mfma_f32_16x16x32_bf16(kf[kt4], qfrag, sa, 0, 0, 0);
                float s0 = sa[0], s1 = sa[1], s2 = sa[2], s3 = sa[3];
                if (maskbf) {
                    s0 += __uint_as_float(mreg[kt].x << 16);
                    s1 += __uint_as_float(mreg[kt].x & 0xFFFF0000u);
                    s2 += __uint_as_float(mreg[kt].y << 16);
                    s3 += __uint_as_float(mreg[kt].y & 0xFFFF0000u);
                }
                float p0 = EXP2(s0), p1 = EXP2(s1), p2 = EXP2(s2), p3 = EXP2(s3);
                lsum += (p0 + p1) + (p2 + p3);
                uint2 pw;
                pw.x = pk2(p0, p1);
                pw.y = pk2(p2, p3);
                *reinterpret_cast<uint2*>(&Pl[wave][l16 * 136 + kt * 16 + quad * 4]) = pw;
            }
        }

        // PV phase (reads Vt[it&1] + own-wave Pl)
#pragma unroll
        for (int c = 0; c < 4; ++c) {
            bf16x8 pa = *reinterpret_cast<const bf16x8*>(
                &Pl[wave][l16 * 136 + c * 32 + quad * 8]);
#pragma unroll
            for (int dt = 0; dt < 2; ++dt) {
                bf16x8 vf = *reinterpret_cast<const bf16x8*>(
                    &Vt[it & 1][(dt * 16 + l16) * 136 + c * 32 + quad * 8]);
                acc_o[dt] = __builtin_amdgcn_mfma_f32_16x16x32_bf16(pa, vf, acc_o[dt], 0, 0, 0);
            }
        }

        if (it < 7) {
            const unsigned int* wa = reinterpret_cast<const unsigned int*>(&ua);
            const unsigned int* wb = reinterpret_cast<const unsigned int*>(&ub);
#pragma unroll
            for (int i = 0; i < 8; ++i) {
                unsigned int x16 = (wa[i >> 1] >> ((i & 1) * 16)) & 0xFFFF;
                unsigned int y16 = (wb[i >> 1] >> ((i & 1) * 16)) & 0xFFFF;
                *reinterpret_cast<unsigned int*>(&Vt[(it + 1) & 1][(dq * 8 + i) * 136 + 2 * kp]) =
                    x16 | (y16 << 16);
            }
        }
    }

    // lsum: per-lane partial is for q=l16; sum the 4 quad groups
    lsum += __shfl_xor(lsum, 16);
    lsum += __shfl_xor(lsum, 32);
    // redistribute: epilogue lane needs lsum(q = quad*4+r)
    float ls[4];
#pragma unroll
    for (int r = 0; r < 4; ++r) ls[r] = __shfl(lsum, quad * 4 + r);

#pragma unroll
    for (int dt = 0; dt < 2; ++dt)
#pragma unroll
        for (int r = 0; r < 4; ++r) {
            float v = acc_o[dt][r] / ls[r];
            long oi = ((long)b * nq + qbase + quad * 4 + r) * E_ + h * KD_ + dt * 16 + l16;
            if (lepe) v += lepe[oi];
            out[oi] = f2bf(v);
        }
}

extern "C" void kernel_launch(void* const* d_in, const int* in_sizes, int n_in,
                              void* d_out, int out_size, void* d_ws, size_t ws_size,
                              hipStream_t stream) {
    const float* x        = (const float*)d_in[0];
    const float* queries  = (const float*)d_in[1];
    const float* sinp     = (const float*)d_in[2];
    const float* cosp     = (const float*)d_in[3];
    const float* mask     = (const float*)d_in[4];
    const float* ln1_g    = (const float*)d_in[5];
    const float* ln1_b    = (const float*)d_in[6];
    const float* ln2_g    = (const float*)d_in[7];
    const float* ln2_b    = (const float*)d_in[8];
    const float* wq       = (const float*)d_in[9];
    const float* bq       = (const float*)d_in[10];
    const float* wk       = (const float*)d_in[11];
    const float* bk       = (const float*)d_in[12];
    const float* wv       = (const float*)d_in[13];
    const float* bv       = (const float*)d_in[14];
    const float* lepe_w   = (const float*)d_in[15];
    const float* lepe_b   = (const float*)d_in[16];
    const float* wo       = (const float*)d_in[17];
    const float* bo       = (const float*)d_in[18];
    const float* fc1_w    = (const float*)d_in[19];
    const float* fc1_b    = (const float*)d_in[20];
    const float* fc2_w    = (const float*)d_in[21];
    const float* fc2_b    = (const float*)d_in[22];
    const float* pos_w    = (const float*)d_in[23];
    const float* pos_b    = (const float*)d_in[24];
    const float* ca_in_w  = (const float*)d_in[25];
    const float* ca_in_b  = (const float*)d_in[26];
    const float* ca_out_w = (const float*)d_in[27];
    const float* ca_out_b = (const float*)d_in[28];

    float* ws = (float*)d_ws;
    const long SZ = (long)B_ * L_ * E_;       // 2,097,152
    float* X    = ws;
    float* Vbf  = ws + SZ;
    float* LEP  = ws + 2 * SZ;
    float* Q2   = LEP;
    ushort_t* U = (ushort_t*)(ws + 3 * SZ);
    ushort_t* T0    = U;               // HN1 -> ATT -> HN2 -> Xb
    ushort_t* Qb_u  = U + SZ;
    ushort_t* Kb_u  = U + 2 * SZ;
    ushort_t* Vb_u  = U + 3 * SZ;
    ushort_t* HID_u = U + 4 * SZ;      // 4*SZ; MB alias
    ushort_t* MB_u  = HID_u;
    ushort_t* WB    = U + 8 * SZ;      // bf16 weights [1,048,576]
    float* LWT      = (float*)(WB + 1048576);   // 25*256 f32
    float* PWT      = LWT + 6400;               // 9*256 f32
    // CA aliases:
    ushort_t* KV_u   = U + SZ;
    ushort_t* QLN_u  = Vb_u;
    ushort_t* QP_u   = Vb_u + 131072;
    ushort_t* CAO_u  = Vb_u + 262144;
    ushort_t* QHID_u = Vb_u + 393216;
    ushort_t* wqB    = WB;
    ushort_t* wkB    = WB + 65536;
    ushort_t* wvB    = WB + 131072;
    ushort_t* woB    = WB + 196608;
    ushort_t* fc1B   = WB + 262144;
    ushort_t* fc2B   = WB + 524288;
    ushort_t* cainB  = WB + 786432;
    ushort_t* caoutB = WB + 983040;

    float* XOUT = (float*)d_out;
    float* QOUT = (float*)d_out + 2097152;

    dim3 blk(256);
    const int rows = B_ * L_;  // 8192
    const float* Z = nullptr;
    const float KSCL = SCALING_ * LOG2E_;   // fold log2e into K so exp == v_exp

    WTab wt;
    wt.src[0] = wq; wt.src[1] = wk; wt.src[2] = wv; wt.src[3] = wo;
    wt.src[4] = fc1_w; wt.src[5] = fc2_w; wt.src[6] = ca_in_w; wt.src[7] = ca_out_w;

    // ---- prep ----
    dwT_kernel<<<1, blk, 0, stream>>>(lepe_w, pos_w, LWT, PWT);
    wconv_kernel<<<1024, blk, 0, stream>>>(wt, WB);
    maskcvt_kernel<<<8192, blk, 0, stream>>>(mask, MB_u);
    posconv_ln2<<<2048, blk, 0, stream>>>(x, PWT, pos_b, ln1_g, ln1_b, X, T0);

    // ---- main path ----
    gemm2<0,1><<<dim3(128, 4), blk, 0, stream>>>(T0, wqB, bq, Qb_u, nullptr, Z, rows, 256, 256, 1.0f, 0, sinp, cosp);
    gemm2<0,1><<<dim3(128, 4), blk, 0, stream>>>(T0, wkB, bk, Kb_u, nullptr, Z, rows, 256, 256, KSCL, 256, sinp, cosp);
    gemm2<0,0><<<dim3(128, 4), blk, 0, stream>>>(T0, wvB, bv, Vb_u, Vbf, Z, rows, 256, 256, 1.0f, 0, Z, Z);
    lepe2<<<2048, blk, 0, stream>>>(Vbf, LWT, lepe_b, LEP);
    attn4<<<dim3(16, 8, 8), blk, 0, stream>>>(Qb_u, 256, Kb_u, 256, Vb_u, 256, MB_u, LEP, T0, L_);
    gemm2<0,0><<<dim3(128, 4), blk, 0, stream>>>(T0, woB, bo, nullptr, X, X, rows, 256, 256, 1.0f, 0, Z, Z);
    ln2<<<2048, blk, 0, stream>>>(X, ln2_g, ln2_b, T0);
    gemm2<1,0><<<dim3(128, 16), blk, 0, stream>>>(T0, fc1B, fc1_b, HID_u, nullptr, Z, rows, 1024, 256, 1.0f, 0, Z, Z);
    gemm2<0,0><<<dim3(128, 4), blk, 0, stream>>>(HID_u, fc2B, fc2_b, T0, XOUT, X, rows, 256, 1024, 1.0f, 0, Z, Z);

    // ---- cross-attention path (A = bf16 final x in T0) ----
    ln2<<<128, blk, 0, stream>>>(queries, ln1_g, ln1_b, QLN_u);
    gemm2<0,0><<<dim3(8, 4), blk, 0, stream>>>(QLN_u, cainB, ca_in_b, QP_u, nullptr, Z, 512, 256, 256, 1.0f, 0, Z, Z);
    gemm2<0,0><<<dim3(128, 8), blk, 0, stream>>>(T0, cainB + 65536, ca_in_b + 256, KV_u, nullptr, Z, rows, 512, 256, KSCL, 256, Z, Z);
    attn4<<<dim3(1, 8, 8), blk, 0, stream>>>(QP_u, 256, KV_u, 512, KV_u + 256, 512, nullptr, nullptr, CAO_u, NQ_);
    gemm2<0,0><<<dim3(8, 4), blk, 0, stream>>>(CAO_u, caoutB, ca_out_b, nullptr, Q2, queries, 512, 256, 256, 1.0f, 0, Z, Z);
    ln2<<<128, blk, 0, stream>>>(Q2, ln2_g, ln2_b, QLN_u);
    gemm2<1,0><<<dim3(8, 16), blk, 0, stream>>>(QLN_u, fc1B, fc1_b, QHID_u, nullptr, Z, 512, 1024, 256, 1.0f, 0, Z, Z);
    gemm2<0,0><<<dim3(8, 4), blk, 0, stream>>>(QHID_u, fc2B, fc2_b, nullptr, QOUT, Q2, 512, 256, 1024, 1.0f, 0, Z, Z);
}

// Round 9
// 338.527 us; speedup vs baseline: 1.0974x; 1.0974x over previous
//
#include <hip/hip_runtime.h>
#include <hip/hip_bf16.h>

#define B_      8
#define HH      32
#define WW      32
#define E_      256
#define HEADS_  8
#define KD_     32
#define FFN_    1024
#define NQ_     64
#define L_      1024
#define SCALING_ 0.17677669529663687f
#define LOG2E_  1.44269504088896340736f
#define EPS_    1e-6f

typedef short bf16x8 __attribute__((ext_vector_type(8)));
typedef float f32x4 __attribute__((ext_vector_type(4)));
typedef unsigned short ushort_t;

#if __has_builtin(__builtin_amdgcn_exp2f)
#define EXP2(x) __builtin_amdgcn_exp2f(x)
#else
#define EXP2(x) exp2f(x)
#endif

__device__ __forceinline__ ushort_t f2bf(float f) {
    __hip_bfloat16 h = __float2bfloat16(f);
    return *reinterpret_cast<ushort_t*>(&h);
}
__device__ __forceinline__ unsigned int pk2(float a, float b) {
    __hip_bfloat162 h = __float22bfloat162_rn(float2{a, b});
    return *reinterpret_cast<unsigned int*>(&h);
}

// ---- fused 3x3 depthwise conv + residual + LN (wave per row) ------------
__global__ __launch_bounds__(256) void posconv_ln2(
        const float* __restrict__ x, const float* __restrict__ PWT,
        const float* __restrict__ bias, const float* __restrict__ g,
        const float* __restrict__ bb, float* __restrict__ X, ushort_t* __restrict__ HN) {
    int tid = threadIdx.x;
    int wave = tid >> 6, lane = tid & 63;
    int b = blockIdx.x >> 8, rem = blockIdx.x & 255;
    int hh = rem >> 3, wg = rem & 7;
    int ww = wg * 4 + wave;
    int e = lane * 4;
    long row = ((long)(b * HH + hh)) * WW + ww;

    float4 bi = *reinterpret_cast<const float4*>(bias + e);
    float ax = bi.x, ay = bi.y, az = bi.z, aw = bi.w;
#pragma unroll
    for (int dh = 0; dh < 3; ++dh) {
        int h2 = hh + dh - 1; if (h2 < 0 || h2 >= HH) continue;
        float rx = 0.f, ry = 0.f, rz = 0.f, rw = 0.f;
#pragma unroll
        for (int dw = 0; dw < 3; ++dw) {
            int w2 = ww + dw - 1; if (w2 < 0 || w2 >= WW) continue;
            float4 v = *reinterpret_cast<const float4*>(x + (((long)(b * HH + h2)) * WW + w2) * E_ + e);
            float4 wt = *reinterpret_cast<const float4*>(PWT + (dh * 3 + dw) * 256 + e);
            rx += v.x * wt.x; ry += v.y * wt.y; rz += v.z * wt.z; rw += v.w * wt.w;
        }
        ax += rx; ay += ry; az += rz; aw += rw;
    }
    float4 x4 = *reinterpret_cast<const float4*>(x + row * E_ + e);
    float vx = x4.x + ax, vy = x4.y + ay, vz = x4.z + az, vw = x4.w + aw;
    float4 o4 = {vx, vy, vz, vw};
    *reinterpret_cast<float4*>(X + row * E_ + e) = o4;

    float s = vx + vy + vz + vw;
#pragma unroll
    for (int off = 1; off < 64; off <<= 1) s += __shfl_xor(s, off);
    float mean = s * (1.0f / E_);
    float dx = vx - mean, dy = vy - mean, dz = vz - mean, dw_ = vw - mean;
    float s2 = dx * dx + dy * dy + dz * dz + dw_ * dw_;
#pragma unroll
    for (int off = 1; off < 64; off <<= 1) s2 += __shfl_xor(s2, off);
    float r = rsqrtf(s2 * (1.0f / E_) + EPS_);
    float4 g4 = *reinterpret_cast<const float4*>(g + e);
    float4 b4 = *reinterpret_cast<const float4*>(bb + e);
    uint2 p;
    p.x = pk2(dx * r * g4.x + b4.x, dy * r * g4.y + b4.y);
    p.y = pk2(dz * r * g4.z + b4.z, dw_ * r * g4.w + b4.w);
    *reinterpret_cast<uint2*>(HN + row * E_ + e) = p;
}

// ---- 5x5 depthwise conv (wave per row, float4) --------------------------
__global__ __launch_bounds__(256) void lepe2(
        const float* __restrict__ v, const float* __restrict__ LWT,
        const float* __restrict__ bias, float* __restrict__ out) {
    int tid = threadIdx.x;
    int wave = tid >> 6, lane = tid & 63;
    int b = blockIdx.x >> 8, rem = blockIdx.x & 255;
    int hh = rem >> 3, wg = rem & 7;
    int ww = wg * 4 + wave;
    int e = lane * 4;
    long row = ((long)(b * HH + hh)) * WW + ww;

    float4 bi = *reinterpret_cast<const float4*>(bias + e);
    float ax = bi.x, ay = bi.y, az = bi.z, aw = bi.w;
#pragma unroll
    for (int dh = 0; dh < 5; ++dh) {
        int h2 = hh + dh - 2; if (h2 < 0 || h2 >= HH) continue;
        float rx = 0.f, ry = 0.f, rz = 0.f, rw = 0.f;
#pragma unroll
        for (int dw = 0; dw < 5; ++dw) {
            int w2 = ww + dw - 2; if (w2 < 0 || w2 >= WW) continue;
            float4 vv = *reinterpret_cast<const float4*>(v + (((long)(b * HH + h2)) * WW + w2) * E_ + e);
            float4 wt = *reinterpret_cast<const float4*>(LWT + (dh * 5 + dw) * 256 + e);
            rx += vv.x * wt.x; ry += vv.y * wt.y; rz += vv.z * wt.z; rw += vv.w * wt.w;
        }
        ax += rx; ay += ry; az += rz; aw += rw;
    }
    float4 o4 = {ax, ay, az, aw};
    *reinterpret_cast<float4*>(out + row * E_ + e) = o4;
}

// ---- LayerNorm v2: wave per row, f32 -> bf16 ----------------------------
__global__ __launch_bounds__(256) void ln2(
        const float* __restrict__ x, const float* __restrict__ g,
        const float* __restrict__ b, ushort_t* __restrict__ y) {
    int tid = threadIdx.x;
    int wave = tid >> 6, lane = tid & 63;
    long row = (long)blockIdx.x * 4 + wave;
    int e = lane * 4;
    float4 v4 = *reinterpret_cast<const float4*>(x + row * E_ + e);
    float s = v4.x + v4.y + v4.z + v4.w;
#pragma unroll
    for (int off = 1; off < 64; off <<= 1) s += __shfl_xor(s, off);
    float mean = s * (1.0f / E_);
    float dx = v4.x - mean, dy = v4.y - mean, dz = v4.z - mean, dw = v4.w - mean;
    float s2 = dx * dx + dy * dy + dz * dz + dw * dw;
#pragma unroll
    for (int off = 1; off < 64; off <<= 1) s2 += __shfl_xor(s2, off);
    float r = rsqrtf(s2 * (1.0f / E_) + EPS_);
    float4 g4 = *reinterpret_cast<const float4*>(g + e);
    float4 b4 = *reinterpret_cast<const float4*>(b + e);
    uint2 p;
    p.x = pk2(dx * r * g4.x + b4.x, dy * r * g4.y + b4.y);
    p.y = pk2(dz * r * g4.z + b4.z, dw * r * g4.w + b4.w);
    *reinterpret_cast<uint2*>(y + row * E_ + e) = p;
}

// ---- weights -> bf16 + depthwise transpose (block 1024) ------------------
struct WTab { const float* src[8]; };
__global__ void wconv_kernel(WTab t, ushort_t* __restrict__ dst,
                             const float* __restrict__ lepe_w, const float* __restrict__ pos_w,
                             float* __restrict__ LWT, float* __restrict__ PWT) {
    if (blockIdx.x == 1024) {
        int e = threadIdx.x;
#pragma unroll
        for (int tp = 0; tp < 25; ++tp) LWT[tp * 256 + e] = lepe_w[e * 25 + tp];
#pragma unroll
        for (int tp = 0; tp < 9; ++tp) PWT[tp * 256 + e] = pos_w[e * 9 + tp];
        return;
    }
    const int off[9] = {0, 65536, 131072, 196608, 262144, 524288, 786432, 983040, 1048576};
    long base = ((long)blockIdx.x * 256 + threadIdx.x) * 4;
    int r = 0;
#pragma unroll
    for (int i = 1; i < 8; ++i) r = (base >= off[i]) ? i : r;
    const float* s =
        r == 0 ? t.src[0] : r == 1 ? t.src[1] : r == 2 ? t.src[2] : r == 3 ? t.src[3] :
        r == 4 ? t.src[4] : r == 5 ? t.src[5] : r == 6 ? t.src[6] : t.src[7];
    float4 v = *reinterpret_cast<const float4*>(s + (base - off[r]));
    uint2 p;
    p.x = pk2(v.x, v.y);
    p.y = pk2(v.z, v.w);
    *reinterpret_cast<uint2*>(dst + base) = p;
}

// ---- MFMA GEMM v2: BM=64 BN=64 BK=64, bf16 A & W, register prefetch -----
template<int ACT, int THETA>
__global__ __launch_bounds__(256) void gemm2(
        const ushort_t* __restrict__ A, const ushort_t* __restrict__ W,
        const float* __restrict__ bias, ushort_t* __restrict__ Cb,
        float* __restrict__ Cf, const float* __restrict__ resid,
        int M, int N, int K, float scale, int scaleN,
        const float* __restrict__ sinp, const float* __restrict__ cosp) {
    __shared__ __align__(16) ushort_t As[64 * 72];
    __shared__ __align__(16) ushort_t Ws[64 * 72];
    int tid = threadIdx.x;
    int wave = tid >> 6, lane = tid & 63;
    int quad = lane >> 4, l16 = lane & 15;
    int wm = wave >> 1, wn = wave & 1;
    long mBase = (long)blockIdx.x * 64;
    long nBase = (long)blockIdx.y * 64;
    int row = tid >> 3, q = tid & 7;
    int row2 = (tid + 256) >> 3, q2 = (tid + 256) & 7;

    f32x4 acc[2][2];
#pragma unroll
    for (int i = 0; i < 2; ++i)
#pragma unroll
        for (int j = 0; j < 2; ++j) acc[i][j] = (f32x4){0.f, 0.f, 0.f, 0.f};

    int nT = K >> 6;
    uint4 a0 = *reinterpret_cast<const uint4*>(A + (mBase + row) * (long)K + q * 8);
    uint4 a1 = *reinterpret_cast<const uint4*>(A + (mBase + row2) * (long)K + q2 * 8);
    uint4 w0 = *reinterpret_cast<const uint4*>(W + (nBase + row) * (long)K + q * 8);
    uint4 w1 = *reinterpret_cast<const uint4*>(W + (nBase + row2) * (long)K + q2 * 8);

    for (int t = 0; t < nT; ++t) {
        *reinterpret_cast<uint4*>(&As[row * 72 + q * 8]) = a0;
        *reinterpret_cast<uint4*>(&As[row2 * 72 + q2 * 8]) = a1;
        *reinterpret_cast<uint4*>(&Ws[row * 72 + q * 8]) = w0;
        *reinterpret_cast<uint4*>(&Ws[row2 * 72 + q2 * 8]) = w1;
        __syncthreads();
        if (t + 1 < nT) {
            int kt = (t + 1) << 6;
            a0 = *reinterpret_cast<const uint4*>(A + (mBase + row) * (long)K + kt + q * 8);
            a1 = *reinterpret_cast<const uint4*>(A + (mBase + row2) * (long)K + kt + q2 * 8);
            w0 = *reinterpret_cast<const uint4*>(W + (nBase + row) * (long)K + kt + q * 8);
            w1 = *reinterpret_cast<const uint4*>(W + (nBase + row2) * (long)K + kt + q2 * 8);
        }
#pragma unroll
        for (int kk = 0; kk < 2; ++kk) {
            bf16x8 af[2], bfr[2];
#pragma unroll
            for (int i = 0; i < 2; ++i)
                af[i] = *reinterpret_cast<const bf16x8*>(&As[(wm * 32 + i * 16 + l16) * 72 + kk * 32 + quad * 8]);
#pragma unroll
            for (int j = 0; j < 2; ++j)
                bfr[j] = *reinterpret_cast<const bf16x8*>(&Ws[(wn * 32 + j * 16 + l16) * 72 + kk * 32 + quad * 8]);
#pragma unroll
            for (int i = 0; i < 2; ++i)
#pragma unroll
                for (int j = 0; j < 2; ++j)
                    acc[i][j] = __builtin_amdgcn_mfma_f32_16x16x32_bf16(af[i], bfr[j], acc[i][j], 0, 0, 0);
        }
        __syncthreads();
    }

#pragma unroll
    for (int i = 0; i < 2; ++i)
#pragma unroll
        for (int j = 0; j < 2; ++j) {
            long n = nBase + wn * 32 + j * 16 + l16;
            float bn = bias[n];
            float eff = (n < scaleN) ? scale : 1.0f;
#pragma unroll
            for (int r = 0; r < 4; ++r) {
                long m = mBase + wm * 32 + i * 16 + quad * 4 + r;
                float v = (acc[i][j][r] + bn) * eff;
                if (THETA) {
                    float other = __shfl_xor(v, 1);
                    int l = (int)(m & (L_ - 1));
                    int d = (int)(n & 31);
                    float cc = cosp[l * 32 + d], ss = sinp[l * 32 + d];
                    v = v * cc + ((n & 1) ? other : -other) * ss;
                }
                if (ACT) v = 0.5f * v * (1.0f + erff(v * 0.70710678118654752f));
                if (resid) v += resid[m * N + n];
                if (Cf) Cf[m * N + n] = v;
                if (Cb) Cb[m * N + n] = f2bf(v);
            }
        }
}

// ---- fused QKV GEMM: grid (128, 12); sel = by>>2 ------------------------
// q: theta; k: *kscl then theta; v: bf16 + f32 dual write.
__global__ __launch_bounds__(256) void gemm_qkv3(
        const ushort_t* __restrict__ A, const ushort_t* __restrict__ WB,
        const float* __restrict__ bq, const float* __restrict__ bk, const float* __restrict__ bv,
        ushort_t* __restrict__ Qb, ushort_t* __restrict__ Kb, ushort_t* __restrict__ Vb,
        float* __restrict__ Vbf, const float* __restrict__ sinp,
        const float* __restrict__ cosp, float kscl) {
    __shared__ __align__(16) ushort_t As[64 * 72];
    __shared__ __align__(16) ushort_t Ws[64 * 72];
    int tid = threadIdx.x;
    int wave = tid >> 6, lane = tid & 63;
    int quad = lane >> 4, l16 = lane & 15;
    int wm = wave >> 1, wn = wave & 1;
    long mBase = (long)blockIdx.x * 64;
    int sel = blockIdx.y >> 2;
    int nLocBase = (blockIdx.y & 3) * 64;
    const ushort_t* W = WB + ((long)(sel * 256 + nLocBase)) * 256;
    const float* bias = sel == 0 ? bq : (sel == 1 ? bk : bv);
    const int K = 256;
    int row = tid >> 3, q = tid & 7;
    int row2 = (tid + 256) >> 3, q2 = (tid + 256) & 7;

    f32x4 acc[2][2];
#pragma unroll
    for (int i = 0; i < 2; ++i)
#pragma unroll
        for (int j = 0; j < 2; ++j) acc[i][j] = (f32x4){0.f, 0.f, 0.f, 0.f};

    uint4 a0 = *reinterpret_cast<const uint4*>(A + (mBase + row) * (long)K + q * 8);
    uint4 a1 = *reinterpret_cast<const uint4*>(A + (mBase + row2) * (long)K + q2 * 8);
    uint4 w0 = *reinterpret_cast<const uint4*>(W + row * (long)K + q * 8);
    uint4 w1 = *reinterpret_cast<const uint4*>(W + row2 * (long)K + q2 * 8);

    for (int t = 0; t < 4; ++t) {
        *reinterpret_cast<uint4*>(&As[row * 72 + q * 8]) = a0;
        *reinterpret_cast<uint4*>(&As[row2 * 72 + q2 * 8]) = a1;
        *reinterpret_cast<uint4*>(&Ws[row * 72 + q * 8]) = w0;
        *reinterpret_cast<uint4*>(&Ws[row2 * 72 + q2 * 8]) = w1;
        __syncthreads();
        if (t < 3) {
            int kt = (t + 1) << 6;
            a0 = *reinterpret_cast<const uint4*>(A + (mBase + row) * (long)K + kt + q * 8);
            a1 = *reinterpret_cast<const uint4*>(A + (mBase + row2) * (long)K + kt + q2 * 8);
            w0 = *reinterpret_cast<const uint4*>(W + row * (long)K + kt + q * 8);
            w1 = *reinterpret_cast<const uint4*>(W + row2 * (long)K + kt + q2 * 8);
        }
#pragma unroll
        for (int kk = 0; kk < 2; ++kk) {
            bf16x8 af[2], bfr[2];
#pragma unroll
            for (int i = 0; i < 2; ++i)
                af[i] = *reinterpret_cast<const bf16x8*>(&As[(wm * 32 + i * 16 + l16) * 72 + kk * 32 + quad * 8]);
#pragma unroll
            for (int j = 0; j < 2; ++j)
                bfr[j] = *reinterpret_cast<const bf16x8*>(&Ws[(wn * 32 + j * 16 + l16) * 72 + kk * 32 + quad * 8]);
#pragma unroll
            for (int i = 0; i < 2; ++i)
#pragma unroll
                for (int j = 0; j < 2; ++j)
                    acc[i][j] = __builtin_amdgcn_mfma_f32_16x16x32_bf16(af[i], bfr[j], acc[i][j], 0, 0, 0);
        }
        __syncthreads();
    }

    ushort_t* Cb = sel == 0 ? Qb : (sel == 1 ? Kb : Vb);
#pragma unroll
    for (int i = 0; i < 2; ++i)
#pragma unroll
        for (int j = 0; j < 2; ++j) {
            int n = nLocBase + wn * 32 + j * 16 + l16;
            float bn = bias[n];
#pragma unroll
            for (int r = 0; r < 4; ++r) {
                long m = mBase + wm * 32 + i * 16 + quad * 4 + r;
                float v = acc[i][j][r] + bn;
                if (sel == 1) v *= kscl;
                if (sel < 2) {
                    float other = __shfl_xor(v, 1);
                    int l = (int)(m & (L_ - 1));
                    int d = n & 31;
                    float cc = cosp[l * 32 + d], ss = sinp[l * 32 + d];
                    v = v * cc + ((n & 1) ? other : -other) * ss;
                }
                Cb[m * 256 + n] = f2bf(v);
                if (sel == 2) Vbf[m * 256 + n] = v;
            }
        }
}

// ---- MFMA flash attention v5 ---------------------------------------------
// S-orientation (attn3), mask decoupled from MFMA (f32 direct, fma LOG2E,
// exp2), double-buffered Vt, K frag prefetch groups of 4.
__global__ __launch_bounds__(256) void attn5(
        const ushort_t* __restrict__ Q, int qs,
        const ushort_t* __restrict__ K, int ks,
        const ushort_t* __restrict__ V, int vs,
        const float* __restrict__ maskf,
        const float* __restrict__ lepe, ushort_t* __restrict__ out, int nq) {
    __shared__ __align__(16) ushort_t Vt[2][32 * 136];
    __shared__ __align__(16) ushort_t Pl[4][16 * 136];
    int tid = threadIdx.x;
    int wave = tid >> 6, lane = tid & 63;
    int quad = lane >> 4, l16 = lane & 15;
    int qt = blockIdx.x, h = blockIdx.y, b = blockIdx.z;
    int qbase = qt * 64 + wave * 16;

    bf16x8 qfrag = *reinterpret_cast<const bf16x8*>(
        Q + ((long)b * nq + qbase + l16) * qs + h * KD_ + quad * 8);

    f32x4 acc_o[2];
    acc_o[0] = (f32x4){0.f, 0.f, 0.f, 0.f};
    acc_o[1] = (f32x4){0.f, 0.f, 0.f, 0.f};
    float lsum[4] = {0.f, 0.f, 0.f, 0.f};

    int kp = tid & 63;
    int dq = tid >> 6;

    const ushort_t* vp = V + ((long)b * L_ + 2 * kp) * vs + h * KD_ + dq * 8;
    uint4 ua = *reinterpret_cast<const uint4*>(vp);
    uint4 ub = *reinterpret_cast<const uint4*>(vp + vs);
    {
        const unsigned int* wa = reinterpret_cast<const unsigned int*>(&ua);
        const unsigned int* wb = reinterpret_cast<const unsigned int*>(&ub);
#pragma unroll
        for (int i = 0; i < 8; ++i) {
            unsigned int x16 = (wa[i >> 1] >> ((i & 1) * 16)) & 0xFFFF;
            unsigned int y16 = (wb[i >> 1] >> ((i & 1) * 16)) & 0xFFFF;
            *reinterpret_cast<unsigned int*>(&Vt[0][(dq * 8 + i) * 136 + 2 * kp]) =
                x16 | (y16 << 16);
        }
    }

    for (int it = 0; it < 8; ++it) {
        int kb = it * 128;
        __syncthreads();
        if (it < 7) {
            const ushort_t* vn = V + ((long)b * L_ + kb + 128 + 2 * kp) * vs + h * KD_ + dq * 8;
            ua = *reinterpret_cast<const uint4*>(vn);
            ub = *reinterpret_cast<const uint4*>(vn + vs);
        }

        // S phase: two groups of 4 key-tiles; mask loads decoupled from MFMA
#pragma unroll
        for (int g = 0; g < 2; ++g) {
            bf16x8 kf[4];
            float mr[4][4];
#pragma unroll
            for (int kt4 = 0; kt4 < 4; ++kt4)
                kf[kt4] = *reinterpret_cast<const bf16x8*>(
                    K + ((long)b * L_ + kb + (g * 4 + kt4) * 16 + l16) * ks + h * KD_ + quad * 8);
            if (maskf) {
#pragma unroll
                for (int kt4 = 0; kt4 < 4; ++kt4)
#pragma unroll
                    for (int r = 0; r < 4; ++r)
                        mr[kt4][r] = maskf[((long)h * L_ + qbase + quad * 4 + r) * L_ +
                                           kb + (g * 4 + kt4) * 16 + l16];
            }
#pragma unroll
            for (int kt4 = 0; kt4 < 4; ++kt4) {
                int kcol = (g * 4 + kt4) * 16;
                f32x4 sa = (f32x4){0.f, 0.f, 0.f, 0.f};
                sa = __builtin_amdgcn_mfma_f32_16x16x32_bf16(qfrag, kf[kt4], sa, 0, 0, 0);
#pragma unroll
                for (int r = 0; r < 4; ++r) {
                    float s = maskf ? fmaf(mr[kt4][r], LOG2E_, sa[r]) : sa[r];
                    float p = EXP2(s);
                    lsum[r] += p;
                    Pl[wave][(quad * 4 + r) * 136 + kcol + l16] = f2bf(p);
                }
            }
        }

        // PV phase
#pragma unroll
        for (int c = 0; c < 4; ++c) {
            bf16x8 pa = *reinterpret_cast<const bf16x8*>(
                &Pl[wave][l16 * 136 + c * 32 + quad * 8]);
#pragma unroll
            for (int dt = 0; dt < 2; ++dt) {
                bf16x8 vf = *reinterpret_cast<const bf16x8*>(
                    &Vt[it & 1][(dt * 16 + l16) * 136 + c * 32 + quad * 8]);
                acc_o[dt] = __builtin_amdgcn_mfma_f32_16x16x32_bf16(pa, vf, acc_o[dt], 0, 0, 0);
            }
        }

        if (it < 7) {
            const unsigned int* wa = reinterpret_cast<const unsigned int*>(&ua);
            const unsigned int* wb = reinterpret_cast<const unsigned int*>(&ub);
#pragma unroll
            for (int i = 0; i < 8; ++i) {
                unsigned int x16 = (wa[i >> 1] >> ((i & 1) * 16)) & 0xFFFF;
                unsigned int y16 = (wb[i >> 1] >> ((i & 1) * 16)) & 0xFFFF;
                *reinterpret_cast<unsigned int*>(&Vt[(it + 1) & 1][(dq * 8 + i) * 136 + 2 * kp]) =
                    x16 | (y16 << 16);
            }
        }
    }

#pragma unroll
    for (int off = 1; off < 16; off <<= 1) {
#pragma unroll
        for (int r = 0; r < 4; ++r) lsum[r] += __shfl_xor(lsum[r], off);
    }

#pragma unroll
    for (int dt = 0; dt < 2; ++dt)
#pragma unroll
        for (int r = 0; r < 4; ++r) {
            float v = acc_o[dt][r] / lsum[r];
            long oi = ((long)b * nq + qbase + quad * 4 + r) * E_ + h * KD_ + dt * 16 + l16;
            if (lepe) v += lepe[oi];
            out[oi] = f2bf(v);
        }
}

extern "C" void kernel_launch(void* const* d_in, const int* in_sizes, int n_in,
                              void* d_out, int out_size, void* d_ws, size_t ws_size,
                              hipStream_t stream) {
    const float* x        = (const float*)d_in[0];
    const float* queries  = (const float*)d_in[1];
    const float* sinp     = (const float*)d_in[2];
    const float* cosp     = (const float*)d_in[3];
    const float* mask     = (const float*)d_in[4];
    const float* ln1_g    = (const float*)d_in[5];
    const float* ln1_b    = (const float*)d_in[6];
    const float* ln2_g    = (const float*)d_in[7];
    const float* ln2_b    = (const float*)d_in[8];
    const float* wq       = (const float*)d_in[9];
    const float* bq       = (const float*)d_in[10];
    const float* wk       = (const float*)d_in[11];
    const float* bk       = (const float*)d_in[12];
    const float* wv       = (const float*)d_in[13];
    const float* bv       = (const float*)d_in[14];
    const float* lepe_w   = (const float*)d_in[15];
    const float* lepe_b   = (const float*)d_in[16];
    const float* wo       = (const float*)d_in[17];
    const float* bo       = (const float*)d_in[18];
    const float* fc1_w    = (const float*)d_in[19];
    const float* fc1_b    = (const float*)d_in[20];
    const float* fc2_w    = (const float*)d_in[21];
    const float* fc2_b    = (const float*)d_in[22];
    const float* pos_w    = (const float*)d_in[23];
    const float* pos_b    = (const float*)d_in[24];
    const float* ca_in_w  = (const float*)d_in[25];
    const float* ca_in_b  = (const float*)d_in[26];
    const float* ca_out_w = (const float*)d_in[27];
    const float* ca_out_b = (const float*)d_in[28];

    float* ws = (float*)d_ws;
    const long SZ = (long)B_ * L_ * E_;       // 2,097,152
    float* X    = ws;
    float* Vbf  = ws + SZ;
    float* LEP  = ws + 2 * SZ;
    float* Q2   = LEP;
    ushort_t* U = (ushort_t*)(ws + 3 * SZ);
    ushort_t* T0    = U;               // HN1 -> ATT -> HN2 -> Xb
    ushort_t* Qb_u  = U + SZ;
    ushort_t* Kb_u  = U + 2 * SZ;
    ushort_t* Vb_u  = U + 3 * SZ;
    ushort_t* HID_u = U + 4 * SZ;      // 4*SZ
    ushort_t* WB    = U + 8 * SZ;      // bf16 weights [1,048,576]
    float* LWT      = (float*)(WB + 1048576);   // 25*256 f32
    float* PWT      = LWT + 6400;               // 9*256 f32
    // CA aliases:
    ushort_t* KV_u   = U + SZ;
    ushort_t* QLN_u  = Vb_u;
    ushort_t* QP_u   = Vb_u + 131072;
    ushort_t* CAO_u  = Vb_u + 262144;
    ushort_t* QHID_u = Vb_u + 393216;
    ushort_t* wqB    = WB;
    ushort_t* woB    = WB + 196608;
    ushort_t* fc1B   = WB + 262144;
    ushort_t* fc2B   = WB + 524288;
    ushort_t* cainB  = WB + 786432;
    ushort_t* caoutB = WB + 983040;

    float* XOUT = (float*)d_out;
    float* QOUT = (float*)d_out + 2097152;

    dim3 blk(256);
    const int rows = B_ * L_;  // 8192
    const float* Z = nullptr;
    const float KSCL = SCALING_ * LOG2E_;   // fold log2e into K so softmax uses exp2

    WTab wt;
    wt.src[0] = wq; wt.src[1] = wk; wt.src[2] = wv; wt.src[3] = wo;
    wt.src[4] = fc1_w; wt.src[5] = fc2_w; wt.src[6] = ca_in_w; wt.src[7] = ca_out_w;

    // ---- prep ----
    wconv_kernel<<<1025, blk, 0, stream>>>(wt, WB, lepe_w, pos_w, LWT, PWT);
    posconv_ln2<<<2048, blk, 0, stream>>>(x, PWT, pos_b, ln1_g, ln1_b, X, T0);

    // ---- main path ----
    gemm_qkv3<<<dim3(128, 12), blk, 0, stream>>>(T0, wqB, bq, bk, bv, Qb_u, Kb_u, Vb_u,
                                                 Vbf, sinp, cosp, KSCL);
    lepe2<<<2048, blk, 0, stream>>>(Vbf, LWT, lepe_b, LEP);
    attn5<<<dim3(16, 8, 8), blk, 0, stream>>>(Qb_u, 256, Kb_u, 256, Vb_u, 256, mask, LEP, T0, L_);
    gemm2<0,0><<<dim3(128, 4), blk, 0, stream>>>(T0, woB, bo, nullptr, X, X, rows, 256, 256, 1.0f, 0, Z, Z);
    ln2<<<2048, blk, 0, stream>>>(X, ln2_g, ln2_b, T0);
    gemm2<1,0><<<dim3(128, 16), blk, 0, stream>>>(T0, fc1B, fc1_b, HID_u, nullptr, Z, rows, 1024, 256, 1.0f, 0, Z, Z);
    gemm2<0,0><<<dim3(128, 4), blk, 0, stream>>>(HID_u, fc2B, fc2_b, T0, XOUT, X, rows, 256, 1024, 1.0f, 0, Z, Z);

    // ---- cross-attention path (A = bf16 final x in T0) ----
    ln2<<<128, blk, 0, stream>>>(queries, ln1_g, ln1_b, QLN_u);
    gemm2<0,0><<<dim3(8, 4), blk, 0, stream>>>(QLN_u, cainB, ca_in_b, QP_u, nullptr, Z, 512, 256, 256, 1.0f, 0, Z, Z);
    gemm2<0,0><<<dim3(128, 8), blk, 0, stream>>>(T0, cainB + 65536, ca_in_b + 256, KV_u, nullptr, Z, rows, 512, 256, KSCL, 256, Z, Z);
    attn5<<<dim3(1, 8, 8), blk, 0, stream>>>(QP_u, 256, KV_u, 512, KV_u + 256, 512, Z, Z, CAO_u, NQ_);
    gemm2<0,0><<<dim3(8, 4), blk, 0, stream>>>(CAO_u, caoutB, ca_out_b, nullptr, Q2, queries, 512, 256, 256, 1.0f, 0, Z, Z);
    ln2<<<128, blk, 0, stream>>>(Q2, ln2_g, ln2_b, QLN_u);
    gemm2<1,0><<<dim3(8, 16), blk, 0, stream>>>(QLN_u, fc1B, fc1_b, QHID_u, nullptr, Z, 512, 1024, 256, 1.0f, 0, Z, Z);
    gemm2<0,0><<<dim3(8, 4), blk, 0, stream>>>(QHID_u, fc2B, fc2_b, nullptr, QOUT, Q2, 512, 256, 1024, 1.0f, 0, Z, Z);
}